// Round 7
// baseline (1234.386 us; speedup 1.0000x reference)
//
#include <hip/hip_runtime.h>
#include <stdint.h>

#define T_TOK 32768
#define DIM   1024
#define NEXP  8
#define DFFN  2048
#define MAXROWS 67584   // 264*256 >= 65536 + 8*255, multiple of 256
#define NBLK  128       // T_TOK / 256
#define NT1 16          // DIM/64 K-tiles for gemm1
#define NT2 32          // DFFN/64 K-tiles for gemm2

typedef __bf16 bf16x8 __attribute__((ext_vector_type(8)));
typedef float  f32x16 __attribute__((ext_vector_type(16)));
typedef unsigned short u16x8 __attribute__((ext_vector_type(8)));

__device__ __forceinline__ unsigned short f2bf(float f) {
  unsigned u = __float_as_uint(f);
  unsigned r = (u + 0x7fffu + ((u >> 16) & 1u)) >> 16;
  return (unsigned short)r;
}
__device__ __forceinline__ float bf2f(unsigned short u) {
  return __uint_as_float(((unsigned)u) << 16);
}

__device__ __forceinline__ void gload16(const void* g, void* l) {
  __builtin_amdgcn_global_load_lds(
      (__attribute__((address_space(1))) void*)(uintptr_t)g,
      (__attribute__((address_space(3))) void*)(uint32_t)(uintptr_t)l,
      16, 0, 0);
}

// XCD-aware remap, M-chunked: XCD owns contiguous mb range, nb fastest.
__device__ __forceinline__ void xcd_remap(int NX, int NY, int& nb, int& mb) {
  int orig = blockIdx.y * NX + blockIdx.x;
  int q = (NX * NY) >> 3;
  int wgid = (orig & 7) * q + (orig >> 3);
  mb = wgid / NX;
  nb = wgid % NX;
}

// ---------------- routing (hierarchical, no global atomics) ----------------
__global__ void route_kernel(const float* __restrict__ gating, int* __restrict__ sel,
                             float* __restrict__ selw, int* __restrict__ blockHist) {
  __shared__ int hist[NEXP];
  const int tid = threadIdx.x;
  if (tid < NEXP) hist[tid] = 0;
  __syncthreads();
  int t = blockIdx.x * 256 + tid;
  float4 a = ((const float4*)gating)[t * 2];
  float4 b = ((const float4*)gating)[t * 2 + 1];
  float l[8] = {a.x, a.y, a.z, a.w, b.x, b.y, b.z, b.w};
  int i0 = 0; float b0 = l[0];
#pragma unroll
  for (int i = 1; i < 8; ++i) if (l[i] > b0) { b0 = l[i]; i0 = i; }
  int i1 = -1; float b1 = -1e30f;
#pragma unroll
  for (int i = 0; i < 8; ++i) if (i != i0 && l[i] > b1) { b1 = l[i]; i1 = i; }
  float e1 = __expf(b1 - b0);
  float w0 = 1.f / (1.f + e1);
  float w1 = 1.f - w0;
  sel[2 * t] = i0;  sel[2 * t + 1] = i1;
  selw[2 * t] = w0; selw[2 * t + 1] = w1;
  atomicAdd(&hist[i0], 1);
  atomicAdd(&hist[i1], 1);
  __syncthreads();
  if (tid < NEXP) blockHist[blockIdx.x * NEXP + tid] = hist[tid];
}

__global__ void plan_kernel(const int* __restrict__ blockHist,
                            int* __restrict__ padOff, int* __restrict__ base) {
  __shared__ int totals[NEXP];
  const int tid = threadIdx.x;
  if (tid < NEXP) {
    int s = 0;
    for (int b = 0; b < NBLK; ++b) s += blockHist[b * NEXP + tid];
    totals[tid] = s;
  }
  __syncthreads();
  if (tid == 0) {
    int off = 0;
    for (int e = 0; e < NEXP; ++e) { padOff[e] = off; off += (totals[e] + 255) & ~255; }
    padOff[NEXP] = off;
  }
  if (tid < NEXP) {
    int off = 0;
    for (int e = 0; e < tid; ++e) off += (totals[e] + 255) & ~255;
    int run = off;
    for (int b = 0; b < NBLK; ++b) { base[b * NEXP + tid] = run; run += blockHist[b * NEXP + tid]; }
  }
}

__global__ void fill_kernel(int* __restrict__ rowTok, int* __restrict__ rowSlot) {
  int i = blockIdx.x * 256 + threadIdx.x;
  if (i < MAXROWS) { rowTok[i] = 0; rowSlot[i] = -1; }
}

__global__ void scatter_kernel(const int* __restrict__ sel, const int* __restrict__ base,
                               int* __restrict__ rowTok, int* __restrict__ rowSlot) {
  __shared__ int cur[NEXP];
  const int tid = threadIdx.x;
  if (tid < NEXP) cur[tid] = 0;
  __syncthreads();
  int t = blockIdx.x * 256 + tid;
#pragma unroll
  for (int j = 0; j < 2; ++j) {
    int e = sel[2 * t + j];
    int pos = atomicAdd(&cur[e], 1);
    int r = base[blockIdx.x * NEXP + e] + pos;
    rowTok[r] = t;
    rowSlot[r] = 2 * t + j;
  }
}

// ---------------- fused f32 -> bf16 conversion ----------------
__global__ void cvt3_kernel(const float* __restrict__ s0, unsigned short* __restrict__ d0, int m0,
                            const float* __restrict__ s1, unsigned short* __restrict__ d1, int m1,
                            const float* __restrict__ s2, unsigned short* __restrict__ d2, int m2) {
  int i = blockIdx.x * 256 + threadIdx.x;
  int stride = gridDim.x * 256;
  for (int k = i; k < m0; k += stride) {
    float4 v = ((const float4*)s0)[k];
    ushort4 o; o.x = f2bf(v.x); o.y = f2bf(v.y); o.z = f2bf(v.z); o.w = f2bf(v.w);
    ((ushort4*)d0)[k] = o;
  }
  for (int k = i; k < m1; k += stride) {
    float4 v = ((const float4*)s1)[k];
    ushort4 o; o.x = f2bf(v.x); o.y = f2bf(v.y); o.z = f2bf(v.z); o.w = f2bf(v.w);
    ((ushort4*)d1)[k] = o;
  }
  for (int k = i; k < m2; k += stride) {
    float4 v = ((const float4*)s2)[k];
    ushort4 o; o.x = f2bf(v.x); o.y = f2bf(v.y); o.z = f2bf(v.z); o.w = f2bf(v.w);
    ((ushort4*)d2)[k] = o;
  }
}

// ======== 2-phase 256x256 grouped GEMMs, 32x32x16 MFMA, linear-fragment LDS ====
// 8 waves (2M x 4N), wave tile 128x64, BK=64 (4 ksteps of 16).
// LDS layout (per 128x64 half-tile, 16KB): 16B slot S = ((mf*4+ks)*2+kh)*32+row,
// mf = row_g>>5, row = row_g&31, ks = k>>4, kh = (k>>3)&1. Fragment read =
// 64 consecutive slots -> perfectly coalesced, zero bank conflicts.
// Staged via linear-dest gload_lds with fragment-permuted per-lane source.
// A-frag (32x32x16): row = ln&31, k = (ln>>5)*8+e. B-frag: col = ln&31, same k.
// C/D (m74/m101): col = ln&31, row = (reg&3)+8*(reg>>2)+4*(ln>>5).

#define STG(arr, srcs, buf, ko)                                                   \
  { gload16(srcs[0][0] + (ko), (char*)&arr[(buf)*16384 + 0*8192 + 0*4096 + wv*512]); \
    gload16(srcs[0][1] + (ko), (char*)&arr[(buf)*16384 + 0*8192 + 1*4096 + wv*512]); \
    gload16(srcs[1][0] + (ko), (char*)&arr[(buf)*16384 + 1*8192 + 0*4096 + wv*512]); \
    gload16(srcs[1][1] + (ko), (char*)&arr[(buf)*16384 + 1*8192 + 1*4096 + wv*512]); }
#define LDA(buf, mf, ks) (*(const bf16x8*)&As[(buf)*16384 + wm*8192 + ((mf)*4+(ks))*512 + l32*256 + l31*8])

__global__ __launch_bounds__(512, 1) void gemm1_kernel(
    const unsigned short* __restrict__ xbf, const unsigned short* __restrict__ w13bf,
    const int* __restrict__ rowTok, const int* __restrict__ padOff,
    unsigned short* __restrict__ H) {
  __shared__ __align__(16) unsigned short As[32768];
  __shared__ __align__(16) unsigned short Bs[32768];

  int nb, mb;
  xcd_remap(gridDim.x, gridDim.y, nb, mb);
  const int m0 = mb * 256;
  const int total = padOff[NEXP];
  if (m0 >= total) return;
  int e = 0;
#pragma unroll
  for (int i = 1; i < NEXP; ++i) if (m0 >= padOff[i]) e = i;
  const int n0 = nb * 128;  // gate f-base; up rows at DFFN + n0

  const int tid = threadIdx.x;
  const int wv = tid >> 6, ln = tid & 63;
  const int wm = wv >> 2, wn = wv & 3;
  const int l31 = ln & 31, l32 = ln >> 5;

  // staging source permutation: thread t, instr i stages slot S=i*512+t:
  // row_g = ((i*2+(t>>8))&3)*32 + (t&31); k = ((t>>6)&3)*16 + ((t>>5)&1)*8
  const int koff = ((tid >> 6) & 3) * 16 + ((tid >> 5) & 1) * 8;
  const int r31 = tid & 31, hi2 = (tid >> 8) & 1;
  const size_t wb = (size_t)e * (size_t)(2 * DFFN) * DIM;
  const unsigned short* sA[2][2];
  const unsigned short* sB[2][2];
#pragma unroll
  for (int h = 0; h < 2; ++h)
#pragma unroll
    for (int i = 0; i < 2; ++i) {
      int rg = (i * 2 + hi2) * 32 + r31;
      sA[h][i] = xbf + (size_t)rowTok[m0 + h * 128 + rg] * DIM + koff;
      sB[h][i] = w13bf + wb + (size_t)(h * DFFN + n0 + rg) * DIM + koff;
    }

#define LDB1(buf, nj, ks) (*(const bf16x8*)&Bs[(buf)*16384 + (nj)*8192 + (wn*4+(ks))*512 + l32*256 + l31*8])

  f32x16 acc[4][2] = {};

  // prologue: tile0 A+B, tile1 A; wait tile0 (leave 4 in flight)
  STG(As, sA, 0, 0) STG(Bs, sB, 0, 0) STG(As, sA, 1, 64)
  asm volatile("s_waitcnt vmcnt(4)" ::: "memory");
  __builtin_amdgcn_sched_barrier(0);
  __builtin_amdgcn_s_barrier();

  for (int t = 0; t < NT1; ++t) {
    const int cur = t & 1, nxt = cur ^ 1;
    const int k1 = (t + 1) * 64, k2 = (t + 2) * 64;
    bf16x8 a[4][4], b0[2][2], b1[2][2];
    // ---- phase A: read all A + B ks01 ; stage t+1 B ; MFMA ks01 ----
#pragma unroll
    for (int ks = 0; ks < 4; ++ks)
#pragma unroll
      for (int mf = 0; mf < 4; ++mf) a[ks][mf] = LDA(cur, mf, ks);
#pragma unroll
    for (int ks = 0; ks < 2; ++ks)
#pragma unroll
      for (int nj = 0; nj < 2; ++nj) b0[ks][nj] = LDB1(cur, nj, ks);
    if (t < NT1 - 1) STG(Bs, sB, nxt, k1)
    __builtin_amdgcn_s_barrier();
    __builtin_amdgcn_s_setprio(1);
#pragma unroll
    for (int ks = 0; ks < 2; ++ks)
#pragma unroll
      for (int mi = 0; mi < 4; ++mi)
#pragma unroll
        for (int nj = 0; nj < 2; ++nj)
          acc[mi][nj] = __builtin_amdgcn_mfma_f32_32x32x16_bf16(a[ks][mi], b0[ks][nj], acc[mi][nj], 0, 0, 0);
    __builtin_amdgcn_s_setprio(0);
    // drain remaining A-reads (ks23) so phase B's A-staging can't race them
    asm volatile("s_waitcnt lgkmcnt(0)" ::: "memory");
    __builtin_amdgcn_sched_barrier(0);
    __builtin_amdgcn_s_barrier();
    // ---- phase B: read B ks23 ; stage t+2 A into cur ; MFMA ks23 ----
#pragma unroll
    for (int ks = 0; ks < 2; ++ks)
#pragma unroll
      for (int nj = 0; nj < 2; ++nj) b1[ks][nj] = LDB1(cur, nj, ks + 2);
    if (t < NT1 - 2) STG(As, sA, cur, k2)
    __builtin_amdgcn_s_barrier();
    __builtin_amdgcn_s_setprio(1);
#pragma unroll
    for (int ks = 0; ks < 2; ++ks)
#pragma unroll
      for (int mi = 0; mi < 4; ++mi)
#pragma unroll
        for (int nj = 0; nj < 2; ++nj)
          acc[mi][nj] = __builtin_amdgcn_mfma_f32_32x32x16_bf16(a[ks + 2][mi], b1[ks][nj], acc[mi][nj], 0, 0, 0);
    __builtin_amdgcn_s_setprio(0);
    if (t < NT1 - 2) { asm volatile("s_waitcnt vmcnt(4)" ::: "memory"); }
    else             { asm volatile("s_waitcnt vmcnt(0)" ::: "memory"); }
    __builtin_amdgcn_sched_barrier(0);
    __builtin_amdgcn_s_barrier();
  }

  // epilogue: h = silu(g)*u ; g = acc[mi][0], u = acc[mi][1] (same col)
  const int f = n0 + wn * 32 + l31;
  const int rowb = m0 + wm * 128;
#pragma unroll
  for (int mi = 0; mi < 4; ++mi) {
    f32x16 g = acc[mi][0], u = acc[mi][1];
#pragma unroll
    for (int reg = 0; reg < 16; ++reg) {
      int rl = (reg & 3) + 8 * (reg >> 2) + 4 * l32;
      float gv = g[reg];
      float hv = (gv / (1.f + __expf(-gv))) * u[reg];
      H[(size_t)(rowb + mi * 32 + rl) * DFFN + f] = f2bf(hv);
    }
  }
#undef LDB1
}

__global__ __launch_bounds__(512, 1) void gemm2_kernel(
    const unsigned short* __restrict__ Hb, const unsigned short* __restrict__ w2bf,
    const int* __restrict__ rowSlot, const int* __restrict__ padOff,
    unsigned short* __restrict__ Oslot) {
  __shared__ __align__(16) unsigned short As[32768];
  __shared__ __align__(16) unsigned short Bs[32768];

  int nb, mb;
  xcd_remap(gridDim.x, gridDim.y, nb, mb);
  const int m0 = mb * 256;
  const int total = padOff[NEXP];
  if (m0 >= total) return;
  int e = 0;
#pragma unroll
  for (int i = 1; i < NEXP; ++i) if (m0 >= padOff[i]) e = i;
  const int n0 = nb * 256;

  const int tid = threadIdx.x;
  const int wv = tid >> 6, ln = tid & 63;
  const int wm = wv >> 2, wn = wv & 3;
  const int l31 = ln & 31, l32 = ln >> 5;

  const int koff = ((tid >> 6) & 3) * 16 + ((tid >> 5) & 1) * 8;
  const int r31 = tid & 31, hi2 = (tid >> 8) & 1;
  const size_t wb = (size_t)e * (size_t)DIM * DFFN;
  const unsigned short* sA[2][2];
  const unsigned short* sB[2][2];
#pragma unroll
  for (int h = 0; h < 2; ++h)
#pragma unroll
    for (int i = 0; i < 2; ++i) {
      int rg = (i * 2 + hi2) * 32 + r31;
      sA[h][i] = Hb + (size_t)(m0 + h * 128 + rg) * DFFN + koff;
      sB[h][i] = w2bf + wb + (size_t)(n0 + h * 128 + rg) * DFFN + koff;
    }

#define LDB2(buf, nj, ks) (*(const bf16x8*)&Bs[(buf)*16384 + (wn>>1)*8192 + (((wn*2+(nj))&3)*4+(ks))*512 + l32*256 + l31*8])

  f32x16 acc[4][2] = {};

  STG(As, sA, 0, 0) STG(Bs, sB, 0, 0) STG(As, sA, 1, 64)
  asm volatile("s_waitcnt vmcnt(4)" ::: "memory");
  __builtin_amdgcn_sched_barrier(0);
  __builtin_amdgcn_s_barrier();

  for (int t = 0; t < NT2; ++t) {
    const int cur = t & 1, nxt = cur ^ 1;
    const int k1 = (t + 1) * 64, k2 = (t + 2) * 64;
    bf16x8 a[4][4], b0[2][2], b1[2][2];
    // phase A
#pragma unroll
    for (int ks = 0; ks < 4; ++ks)
#pragma unroll
      for (int mf = 0; mf < 4; ++mf) a[ks][mf] = LDA(cur, mf, ks);
#pragma unroll
    for (int ks = 0; ks < 2; ++ks)
#pragma unroll
      for (int nj = 0; nj < 2; ++nj) b0[ks][nj] = LDB2(cur, nj, ks);
    if (t < NT2 - 1) STG(Bs, sB, nxt, k1)
    __builtin_amdgcn_s_barrier();
    __builtin_amdgcn_s_setprio(1);
#pragma unroll
    for (int ks = 0; ks < 2; ++ks)
#pragma unroll
      for (int mi = 0; mi < 4; ++mi)
#pragma unroll
        for (int nj = 0; nj < 2; ++nj)
          acc[mi][nj] = __builtin_amdgcn_mfma_f32_32x32x16_bf16(a[ks][mi], b0[ks][nj], acc[mi][nj], 0, 0, 0);
    __builtin_amdgcn_s_setprio(0);
    asm volatile("s_waitcnt lgkmcnt(0)" ::: "memory");
    __builtin_amdgcn_sched_barrier(0);
    __builtin_amdgcn_s_barrier();
    // phase B
#pragma unroll
    for (int ks = 0; ks < 2; ++ks)
#pragma unroll
      for (int nj = 0; nj < 2; ++nj) b1[ks][nj] = LDB2(cur, nj, ks + 2);
    if (t < NT2 - 2) STG(As, sA, cur, k2)
    __builtin_amdgcn_s_barrier();
    __builtin_amdgcn_s_setprio(1);
#pragma unroll
    for (int ks = 0; ks < 2; ++ks)
#pragma unroll
      for (int mi = 0; mi < 4; ++mi)
#pragma unroll
        for (int nj = 0; nj < 2; ++nj)
          acc[mi][nj] = __builtin_amdgcn_mfma_f32_32x32x16_bf16(a[ks + 2][mi], b1[ks][nj], acc[mi][nj], 0, 0, 0);
    __builtin_amdgcn_s_setprio(0);
    if (t < NT2 - 2) { asm volatile("s_waitcnt vmcnt(4)" ::: "memory"); }
    else             { asm volatile("s_waitcnt vmcnt(0)" ::: "memory"); }
    __builtin_amdgcn_sched_barrier(0);
    __builtin_amdgcn_s_barrier();
  }

  const int colb = n0 + wn * 64 + l31;
  const int rowb = m0 + wm * 128;
#pragma unroll
  for (int mi = 0; mi < 4; ++mi) {
#pragma unroll
    for (int reg = 0; reg < 16; ++reg) {
      int rl = (reg & 3) + 8 * (reg >> 2) + 4 * l32;
      int row = rowb + mi * 32 + rl;
      int si = rowSlot[row];
      if (si >= 0) {
        unsigned short* op = Oslot + (size_t)si * DIM + colb;
        op[0]  = f2bf(acc[mi][0][reg]);
        op[32] = f2bf(acc[mi][1][reg]);
      }
    }
  }
#undef LDB2
}

// ---------------- combine: out[t] = w0*Oslot[2t] + w1*Oslot[2t+1] ----------------
__global__ void combine_kernel(const unsigned short* __restrict__ Oslot,
                               const float* __restrict__ selw, float* __restrict__ out) {
  int idx = blockIdx.x * 256 + threadIdx.x;
  int t = idx >> 7;
  int c = (idx & 127) << 3;
  u16x8 a = *(const u16x8*)(Oslot + (size_t)(2 * t) * DIM + c);
  u16x8 b = *(const u16x8*)(Oslot + (size_t)(2 * t + 1) * DIM + c);
  float w0 = selw[2 * t], w1 = selw[2 * t + 1];
  float4 o0, o1;
  o0.x = w0 * bf2f(a[0]) + w1 * bf2f(b[0]);
  o0.y = w0 * bf2f(a[1]) + w1 * bf2f(b[1]);
  o0.z = w0 * bf2f(a[2]) + w1 * bf2f(b[2]);
  o0.w = w0 * bf2f(a[3]) + w1 * bf2f(b[3]);
  o1.x = w0 * bf2f(a[4]) + w1 * bf2f(b[4]);
  o1.y = w0 * bf2f(a[5]) + w1 * bf2f(b[5]);
  o1.z = w0 * bf2f(a[6]) + w1 * bf2f(b[6]);
  o1.w = w0 * bf2f(a[7]) + w1 * bf2f(b[7]);
  float4* op = (float4*)(out + (size_t)t * DIM + c);
  op[0] = o0; op[1] = o1;
}

extern "C" void kernel_launch(void* const* d_in, const int* in_sizes, int n_in,
                              void* d_out, int out_size, void* d_ws, size_t ws_size,
                              hipStream_t stream) {
  const float* x      = (const float*)d_in[0];
  const float* gating = (const float*)d_in[1];
  const float* w13    = (const float*)d_in[2];
  const float* w2     = (const float*)d_in[3];
  float* out = (float*)d_out;

  char* ws = (char*)d_ws;
  size_t off = 0;
  auto alloc = [&](size_t bytes) { char* p = ws + off; off += (bytes + 255) & ~(size_t)255; return p; };
  int*   padOff    = (int*)alloc(64);
  int*   blockHist = (int*)alloc((size_t)NBLK * NEXP * 4);
  int*   base      = (int*)alloc((size_t)NBLK * NEXP * 4);
  int*   sel       = (int*)alloc((size_t)2 * T_TOK * 4);
  float* selw      = (float*)alloc((size_t)2 * T_TOK * 4);
  int*   rowTok    = (int*)alloc((size_t)MAXROWS * 4);
  int*   rowSlot   = (int*)alloc((size_t)MAXROWS * 4);
  unsigned short* xbf   = (unsigned short*)alloc((size_t)T_TOK * DIM * 2);           // 64 MiB
  unsigned short* w13bf = (unsigned short*)alloc((size_t)NEXP * 2 * DFFN * DIM * 2); // 64 MiB
  unsigned short* w2bf  = (unsigned short*)alloc((size_t)NEXP * DIM * DFFN * 2);     // 32 MiB
  unsigned short* Hbuf  = (unsigned short*)alloc((size_t)MAXROWS * DFFN * 2);        // 264 MiB
  unsigned short* Oslot = xbf;  // 128 MiB alias over xbf+w13bf (dead after gemm1)

  route_kernel<<<NBLK, 256, 0, stream>>>(gating, sel, selw, blockHist);
  plan_kernel<<<1, 64, 0, stream>>>(blockHist, padOff, base);
  fill_kernel<<<MAXROWS / 256, 256, 0, stream>>>(rowTok, rowSlot);
  scatter_kernel<<<NBLK, 256, 0, stream>>>(sel, base, rowTok, rowSlot);
  cvt3_kernel<<<2048, 256, 0, stream>>>(x, xbf, T_TOK * DIM / 4,
                                        w13, w13bf, NEXP * 2 * DFFN * DIM / 4,
                                        w2, w2bf, NEXP * DIM * DFFN / 4);
  gemm1_kernel<<<dim3(2 * DFFN / 256, MAXROWS / 256), 512, 0, stream>>>(xbf, w13bf, rowTok, padOff, Hbuf);
  gemm2_kernel<<<dim3(DIM / 256, MAXROWS / 256), 512, 0, stream>>>(Hbuf, w2bf, rowSlot, padOff, Oslot);
  combine_kernel<<<T_TOK * DIM / 8 / 256, 256, 0, stream>>>(Oslot, selw, out);
}

// Round 8
// 990.188 us; speedup vs baseline: 1.2466x; 1.2466x over previous
//
#include <hip/hip_runtime.h>
#include <stdint.h>

#define T_TOK 32768
#define DIM   1024
#define NEXP  8
#define DFFN  2048
#define MAXROWS 67584   // 264*256 >= 65536 + 8*255, multiple of 256
#define NBLK  128       // T_TOK / 256
#define NT1 16          // DIM/64 K-tiles for gemm1
#define NT2 32          // DFFN/64 K-tiles for gemm2

typedef __bf16 bf16x8 __attribute__((ext_vector_type(8)));
typedef float  f32x4  __attribute__((ext_vector_type(4)));
typedef unsigned short u16x8 __attribute__((ext_vector_type(8)));

__device__ __forceinline__ unsigned short f2bf(float f) {
  unsigned u = __float_as_uint(f);
  unsigned r = (u + 0x7fffu + ((u >> 16) & 1u)) >> 16;
  return (unsigned short)r;
}
__device__ __forceinline__ float bf2f(unsigned short u) {
  return __uint_as_float(((unsigned)u) << 16);
}

__device__ __forceinline__ void gload16(const void* g, void* l) {
  __builtin_amdgcn_global_load_lds(
      (__attribute__((address_space(1))) void*)(uintptr_t)g,
      (__attribute__((address_space(3))) void*)(uint32_t)(uintptr_t)l,
      16, 0, 0);
}

// XCD-aware remap, M-chunked: XCD owns contiguous mb range, nb fastest.
__device__ __forceinline__ void xcd_remap(int NX, int NY, int& nb, int& mb) {
  int orig = blockIdx.y * NX + blockIdx.x;
  int q = (NX * NY) >> 3;
  int wgid = (orig & 7) * q + (orig >> 3);
  mb = wgid / NX;
  nb = wgid % NX;
}

// ---------------- routing (hierarchical, no global atomics) ----------------
__global__ void route_kernel(const float* __restrict__ gating, int* __restrict__ sel,
                             float* __restrict__ selw, int* __restrict__ blockHist) {
  __shared__ int hist[NEXP];
  const int tid = threadIdx.x;
  if (tid < NEXP) hist[tid] = 0;
  __syncthreads();
  int t = blockIdx.x * 256 + tid;
  float4 a = ((const float4*)gating)[t * 2];
  float4 b = ((const float4*)gating)[t * 2 + 1];
  float l[8] = {a.x, a.y, a.z, a.w, b.x, b.y, b.z, b.w};
  int i0 = 0; float b0 = l[0];
#pragma unroll
  for (int i = 1; i < 8; ++i) if (l[i] > b0) { b0 = l[i]; i0 = i; }
  int i1 = -1; float b1 = -1e30f;
#pragma unroll
  for (int i = 0; i < 8; ++i) if (i != i0 && l[i] > b1) { b1 = l[i]; i1 = i; }
  float e1 = __expf(b1 - b0);
  float w0 = 1.f / (1.f + e1);
  float w1 = 1.f - w0;
  sel[2 * t] = i0;  sel[2 * t + 1] = i1;
  selw[2 * t] = w0; selw[2 * t + 1] = w1;
  atomicAdd(&hist[i0], 1);
  atomicAdd(&hist[i1], 1);
  __syncthreads();
  if (tid < NEXP) blockHist[blockIdx.x * NEXP + tid] = hist[tid];
}

__global__ void plan_kernel(const int* __restrict__ blockHist,
                            int* __restrict__ padOff, int* __restrict__ base) {
  __shared__ int totals[NEXP];
  const int tid = threadIdx.x;
  if (tid < NEXP) {
    int s = 0;
    for (int b = 0; b < NBLK; ++b) s += blockHist[b * NEXP + tid];
    totals[tid] = s;
  }
  __syncthreads();
  if (tid == 0) {
    int off = 0;
    for (int e = 0; e < NEXP; ++e) { padOff[e] = off; off += (totals[e] + 255) & ~255; }
    padOff[NEXP] = off;
  }
  if (tid < NEXP) {
    int off = 0;
    for (int e = 0; e < tid; ++e) off += (totals[e] + 255) & ~255;
    int run = off;
    for (int b = 0; b < NBLK; ++b) { base[b * NEXP + tid] = run; run += blockHist[b * NEXP + tid]; }
  }
}

__global__ void fill_kernel(int* __restrict__ rowTok, int* __restrict__ rowSlot) {
  int i = blockIdx.x * 256 + threadIdx.x;
  if (i < MAXROWS) { rowTok[i] = 0; rowSlot[i] = -1; }
}

__global__ void scatter_kernel(const int* __restrict__ sel, const int* __restrict__ base,
                               int* __restrict__ rowTok, int* __restrict__ rowSlot) {
  __shared__ int cur[NEXP];
  const int tid = threadIdx.x;
  if (tid < NEXP) cur[tid] = 0;
  __syncthreads();
  int t = blockIdx.x * 256 + tid;
#pragma unroll
  for (int j = 0; j < 2; ++j) {
    int e = sel[2 * t + j];
    int pos = atomicAdd(&cur[e], 1);
    int r = base[blockIdx.x * NEXP + e] + pos;
    rowTok[r] = t;
    rowSlot[r] = 2 * t + j;
  }
}

// ---------------- fused f32 -> bf16 conversion ----------------
__global__ void cvt3_kernel(const float* __restrict__ s0, unsigned short* __restrict__ d0, int m0,
                            const float* __restrict__ s1, unsigned short* __restrict__ d1, int m1,
                            const float* __restrict__ s2, unsigned short* __restrict__ d2, int m2) {
  int i = blockIdx.x * 256 + threadIdx.x;
  int stride = gridDim.x * 256;
  for (int k = i; k < m0; k += stride) {
    float4 v = ((const float4*)s0)[k];
    ushort4 o; o.x = f2bf(v.x); o.y = f2bf(v.y); o.z = f2bf(v.z); o.w = f2bf(v.w);
    ((ushort4*)d0)[k] = o;
  }
  for (int k = i; k < m1; k += stride) {
    float4 v = ((const float4*)s1)[k];
    ushort4 o; o.x = f2bf(v.x); o.y = f2bf(v.y); o.z = f2bf(v.z); o.w = f2bf(v.w);
    ((ushort4*)d1)[k] = o;
  }
  for (int k = i; k < m2; k += stride) {
    float4 v = ((const float4*)s2)[k];
    ushort4 o; o.x = f2bf(v.x); o.y = f2bf(v.y); o.z = f2bf(v.z); o.w = f2bf(v.w);
    ((ushort4*)d2)[k] = o;
  }
}

// ======== 8-phase 256x256 grouped GEMM1: gu = x @ w13[e]^T, H = silu(g)*u ========
// 8 waves (2M x 4N), BK=64, LDS 128KB dbuf in half-tiles (128x64), counted vmcnt.
__global__ __launch_bounds__(512, 1) void gemm1_kernel(
    const unsigned short* __restrict__ xbf, const unsigned short* __restrict__ w13bf,
    const int* __restrict__ rowTok, const int* __restrict__ padOff,
    unsigned short* __restrict__ H) {
  __shared__ __align__(16) unsigned short As[2][256][64];
  __shared__ __align__(16) unsigned short Bs[2][256][64];

  int nb, mb;
  xcd_remap(gridDim.x, gridDim.y, nb, mb);
  const int m0 = mb * 256;
  const int total = padOff[NEXP];
  if (m0 >= total) return;
  int e = 0;
#pragma unroll
  for (int i = 1; i < NEXP; ++i) if (m0 >= padOff[i]) e = i;
  const int n0 = nb * 128;  // gate f-base; up rows at DFFN + n0

  const int tid = threadIdx.x;
  const int wv = tid >> 6, ln = tid & 63;
  const int wm = wv >> 2, wn = wv & 3;
  const int lrow = ln & 15, l4 = ln >> 4, ls7 = ln & 7;

  const int gsl = ((tid & 7) ^ ((tid >> 3) & 7)) * 8;
  const int srow = tid >> 3;
  const size_t wb = (size_t)e * (size_t)(2 * DFFN) * DIM;
  const unsigned short* sA[2][2];
  const unsigned short* sB[2][2];
#pragma unroll
  for (int h = 0; h < 2; ++h)
#pragma unroll
    for (int i = 0; i < 2; ++i) {
      int tok = rowTok[m0 + h * 128 + i * 64 + srow];
      sA[h][i] = xbf + (size_t)tok * DIM + gsl;
      sB[h][i] = w13bf + wb + (size_t)(h * DFFN + n0 + i * 64 + srow) * DIM + gsl;
    }

#define STG_A1(buf, h, ko) { gload16(sA[h][0] + (ko), (char*)&As[buf][(h)*128 + wv*8][0]); \
                             gload16(sA[h][1] + (ko), (char*)&As[buf][(h)*128 + 64 + wv*8][0]); }
#define STG_B1(buf, h, ko) { gload16(sB[h][0] + (ko), (char*)&Bs[buf][(h)*128 + wv*8][0]); \
                             gload16(sB[h][1] + (ko), (char*)&Bs[buf][(h)*128 + 64 + wv*8][0]); }
#define LDA1(buf, mi, ks) (*(const bf16x8*)&As[buf][wm*128 + (mi)*16 + lrow][(((ks) + l4) ^ ls7) * 8])
#define LDB1(buf, f, ks)  (*(const bf16x8*)&Bs[buf][((f) >> 1)*128 + wn*32 + ((f) & 1)*16 + lrow][(((ks) + l4) ^ ls7) * 8])
#define MFMA16(A, B0v, B1v, f0, f1)                                              \
  _Pragma("unroll")                                                              \
  for (int mi = 0; mi < 8; ++mi) {                                               \
    acc[mi][f0] = __builtin_amdgcn_mfma_f32_16x16x32_bf16(A[mi], B0v, acc[mi][f0], 0, 0, 0); \
    acc[mi][f1] = __builtin_amdgcn_mfma_f32_16x16x32_bf16(A[mi], B1v, acc[mi][f1], 0, 0, 0); \
  }

  f32x4 acc[8][4] = {};

  STG_A1(0, 0, 0) STG_A1(0, 1, 0) STG_B1(0, 0, 0) STG_B1(0, 1, 0)
  STG_A1(1, 0, 64) STG_A1(1, 1, 64)
  asm volatile("s_waitcnt vmcnt(4)" ::: "memory");
  __builtin_amdgcn_sched_barrier(0);
  __builtin_amdgcn_s_barrier();

  for (int t = 0; t < NT1; ++t) {
    const int cur = t & 1, nxt = cur ^ 1;
    const int k1 = (t + 1) * 64, k2 = (t + 2) * 64;
    bf16x8 a0[8], a1[8], bv0, bv1;
    // phase 0
#pragma unroll
    for (int mi = 0; mi < 8; ++mi) a0[mi] = LDA1(cur, mi, 0);
    bv0 = LDB1(cur, 0, 0); bv1 = LDB1(cur, 1, 0);
    if (t < NT1 - 1) STG_B1(nxt, 0, k1)
    __builtin_amdgcn_s_barrier();
    __builtin_amdgcn_s_setprio(1);
    MFMA16(a0, bv0, bv1, 0, 1)
    __builtin_amdgcn_s_setprio(0);
    __builtin_amdgcn_s_barrier();
    // phase 1
    bv0 = LDB1(cur, 2, 0); bv1 = LDB1(cur, 3, 0);
#pragma unroll
    for (int mi = 0; mi < 8; ++mi) a1[mi] = LDA1(cur, mi, 4);
    if (t < NT1 - 1) STG_B1(nxt, 1, k1)
    __builtin_amdgcn_s_barrier();
    __builtin_amdgcn_s_setprio(1);
    MFMA16(a0, bv0, bv1, 2, 3)
    __builtin_amdgcn_s_setprio(0);
    __builtin_amdgcn_s_barrier();
    // phase 2
    bv0 = LDB1(cur, 0, 4); bv1 = LDB1(cur, 1, 4);
    if (t < NT1 - 2) STG_A1(cur, 0, k2)
    __builtin_amdgcn_s_barrier();
    __builtin_amdgcn_s_setprio(1);
    MFMA16(a1, bv0, bv1, 0, 1)
    __builtin_amdgcn_s_setprio(0);
    __builtin_amdgcn_s_barrier();
    // phase 3
    bv0 = LDB1(cur, 2, 4); bv1 = LDB1(cur, 3, 4);
    if (t < NT1 - 2) STG_A1(cur, 1, k2)
    __builtin_amdgcn_s_barrier();
    __builtin_amdgcn_s_setprio(1);
    MFMA16(a1, bv0, bv1, 2, 3)
    __builtin_amdgcn_s_setprio(0);
    if (t < NT1 - 2) { asm volatile("s_waitcnt vmcnt(4)" ::: "memory"); }
    else             { asm volatile("s_waitcnt vmcnt(0)" ::: "memory"); }
    __builtin_amdgcn_sched_barrier(0);
    __builtin_amdgcn_s_barrier();
  }

  const int fcol = n0 + wn * 32 + lrow;
  const int rowb = m0 + wm * 128 + l4 * 4;
#pragma unroll
  for (int mi = 0; mi < 8; ++mi) {
#pragma unroll
    for (int fj = 0; fj < 2; ++fj) {
      f32x4 g = acc[mi][fj], u = acc[mi][fj + 2];
      int f = fcol + fj * 16;
#pragma unroll
      for (int r = 0; r < 4; ++r) {
        float gv = g[r];
        float hv = (gv / (1.f + __expf(-gv))) * u[r];
        H[(size_t)(rowb + mi * 16 + r) * DFFN + f] = f2bf(hv);
      }
    }
  }
#undef STG_A1
#undef STG_B1
#undef LDA1
#undef LDB1
#undef MFMA16
}

// ======== 8-phase 256x256 grouped GEMM2: Oslot[slot] = H @ w2[e]^T ========
__global__ __launch_bounds__(512, 1) void gemm2_kernel(
    const unsigned short* __restrict__ Hb, const unsigned short* __restrict__ w2bf,
    const int* __restrict__ rowSlot, const int* __restrict__ padOff,
    unsigned short* __restrict__ Oslot) {
  __shared__ __align__(16) unsigned short As[2][256][64];
  __shared__ __align__(16) unsigned short Bs[2][256][64];

  int nb, mb;
  xcd_remap(gridDim.x, gridDim.y, nb, mb);
  const int m0 = mb * 256;
  const int total = padOff[NEXP];
  if (m0 >= total) return;
  int e = 0;
#pragma unroll
  for (int i = 1; i < NEXP; ++i) if (m0 >= padOff[i]) e = i;
  const int n0 = nb * 256;

  const int tid = threadIdx.x;
  const int wv = tid >> 6, ln = tid & 63;
  const int wm = wv >> 2, wn = wv & 3;
  const int lrow = ln & 15, l4 = ln >> 4, ls7 = ln & 7;

  const int gsl = ((tid & 7) ^ ((tid >> 3) & 7)) * 8;
  const int srow = tid >> 3;
  const size_t wb = (size_t)e * (size_t)DIM * DFFN;
  const unsigned short* sA[2][2];
  const unsigned short* sB[2][2];
#pragma unroll
  for (int h = 0; h < 2; ++h)
#pragma unroll
    for (int i = 0; i < 2; ++i) {
      sA[h][i] = Hb + (size_t)(m0 + h * 128 + i * 64 + srow) * DFFN + gsl;
      sB[h][i] = w2bf + wb + (size_t)(n0 + h * 128 + i * 64 + srow) * DFFN + gsl;
    }

#define STG_A2(buf, h, ko) { gload16(sA[h][0] + (ko), (char*)&As[buf][(h)*128 + wv*8][0]); \
                             gload16(sA[h][1] + (ko), (char*)&As[buf][(h)*128 + 64 + wv*8][0]); }
#define STG_B2(buf, h, ko) { gload16(sB[h][0] + (ko), (char*)&Bs[buf][(h)*128 + wv*8][0]); \
                             gload16(sB[h][1] + (ko), (char*)&Bs[buf][(h)*128 + 64 + wv*8][0]); }
#define LDA2(buf, mi, ks) (*(const bf16x8*)&As[buf][wm*128 + (mi)*16 + lrow][(((ks) + l4) ^ ls7) * 8])
#define LDB2(buf, f, ks)  (*(const bf16x8*)&Bs[buf][wn*64 + (f)*16 + lrow][(((ks) + l4) ^ ls7) * 8])
#define MFMA16(A, B0v, B1v, f0, f1)                                              \
  _Pragma("unroll")                                                              \
  for (int mi = 0; mi < 8; ++mi) {                                               \
    acc[mi][f0] = __builtin_amdgcn_mfma_f32_16x16x32_bf16(A[mi], B0v, acc[mi][f0], 0, 0, 0); \
    acc[mi][f1] = __builtin_amdgcn_mfma_f32_16x16x32_bf16(A[mi], B1v, acc[mi][f1], 0, 0, 0); \
  }

  f32x4 acc[8][4] = {};

  STG_A2(0, 0, 0) STG_A2(0, 1, 0) STG_B2(0, 0, 0) STG_B2(0, 1, 0)
  STG_A2(1, 0, 64) STG_A2(1, 1, 64)
  asm volatile("s_waitcnt vmcnt(4)" ::: "memory");
  __builtin_amdgcn_sched_barrier(0);
  __builtin_amdgcn_s_barrier();

  for (int t = 0; t < NT2; ++t) {
    const int cur = t & 1, nxt = cur ^ 1;
    const int k1 = (t + 1) * 64, k2 = (t + 2) * 64;
    bf16x8 a0[8], a1[8], bv0, bv1;
    // phase 0
#pragma unroll
    for (int mi = 0; mi < 8; ++mi) a0[mi] = LDA2(cur, mi, 0);
    bv0 = LDB2(cur, 0, 0); bv1 = LDB2(cur, 1, 0);
    if (t < NT2 - 1) STG_B2(nxt, 0, k1)
    __builtin_amdgcn_s_barrier();
    __builtin_amdgcn_s_setprio(1);
    MFMA16(a0, bv0, bv1, 0, 1)
    __builtin_amdgcn_s_setprio(0);
    __builtin_amdgcn_s_barrier();
    // phase 1
    bv0 = LDB2(cur, 2, 0); bv1 = LDB2(cur, 3, 0);
#pragma unroll
    for (int mi = 0; mi < 8; ++mi) a1[mi] = LDA2(cur, mi, 4);
    if (t < NT2 - 1) STG_B2(nxt, 1, k1)
    __builtin_amdgcn_s_barrier();
    __builtin_amdgcn_s_setprio(1);
    MFMA16(a0, bv0, bv1, 2, 3)
    __builtin_amdgcn_s_setprio(0);
    __builtin_amdgcn_s_barrier();
    // phase 2
    bv0 = LDB2(cur, 0, 4); bv1 = LDB2(cur, 1, 4);
    if (t < NT2 - 2) STG_A2(cur, 0, k2)
    __builtin_amdgcn_s_barrier();
    __builtin_amdgcn_s_setprio(1);
    MFMA16(a1, bv0, bv1, 0, 1)
    __builtin_amdgcn_s_setprio(0);
    __builtin_amdgcn_s_barrier();
    // phase 3
    bv0 = LDB2(cur, 2, 4); bv1 = LDB2(cur, 3, 4);
    if (t < NT2 - 2) STG_A2(cur, 1, k2)
    __builtin_amdgcn_s_barrier();
    __builtin_amdgcn_s_setprio(1);
    MFMA16(a1, bv0, bv1, 2, 3)
    __builtin_amdgcn_s_setprio(0);
    if (t < NT2 - 2) { asm volatile("s_waitcnt vmcnt(4)" ::: "memory"); }
    else             { asm volatile("s_waitcnt vmcnt(0)" ::: "memory"); }
    __builtin_amdgcn_sched_barrier(0);
    __builtin_amdgcn_s_barrier();
  }

  const int colb = n0 + wn * 64 + lrow;
  const int rowb = m0 + wm * 128 + l4 * 4;
#pragma unroll
  for (int mi = 0; mi < 8; ++mi) {
#pragma unroll
    for (int r = 0; r < 4; ++r) {
      int row = rowb + mi * 16 + r;
      int si = rowSlot[row];
      if (si >= 0) {
        unsigned short* op = Oslot + (size_t)si * DIM + colb;
#pragma unroll
        for (int f = 0; f < 4; ++f) op[f * 16] = f2bf(acc[mi][f][r]);
      }
    }
  }
#undef STG_A2
#undef STG_B2
#undef LDA2
#undef LDB2
#undef MFMA16
}

// ---------------- combine: out[t] = w0*Oslot[2t] + w1*Oslot[2t+1] ----------------
__global__ void combine_kernel(const unsigned short* __restrict__ Oslot,
                               const float* __restrict__ selw, float* __restrict__ out) {
  int idx = blockIdx.x * 256 + threadIdx.x;
  int t = idx >> 7;
  int c = (idx & 127) << 3;
  u16x8 a = *(const u16x8*)(Oslot + (size_t)(2 * t) * DIM + c);
  u16x8 b = *(const u16x8*)(Oslot + (size_t)(2 * t + 1) * DIM + c);
  float w0 = selw[2 * t], w1 = selw[2 * t + 1];
  float4 o0, o1;
  o0.x = w0 * bf2f(a[0]) + w1 * bf2f(b[0]);
  o0.y = w0 * bf2f(a[1]) + w1 * bf2f(b[1]);
  o0.z = w0 * bf2f(a[2]) + w1 * bf2f(b[2]);
  o0.w = w0 * bf2f(a[3]) + w1 * bf2f(b[3]);
  o1.x = w0 * bf2f(a[4]) + w1 * bf2f(b[4]);
  o1.y = w0 * bf2f(a[5]) + w1 * bf2f(b[5]);
  o1.z = w0 * bf2f(a[6]) + w1 * bf2f(b[6]);
  o1.w = w0 * bf2f(a[7]) + w1 * bf2f(b[7]);
  float4* op = (float4*)(out + (size_t)t * DIM + c);
  op[0] = o0; op[1] = o1;
}

extern "C" void kernel_launch(void* const* d_in, const int* in_sizes, int n_in,
                              void* d_out, int out_size, void* d_ws, size_t ws_size,
                              hipStream_t stream) {
  const float* x      = (const float*)d_in[0];
  const float* gating = (const float*)d_in[1];
  const float* w13    = (const float*)d_in[2];
  const float* w2     = (const float*)d_in[3];
  float* out = (float*)d_out;

  char* ws = (char*)d_ws;
  size_t off = 0;
  auto alloc = [&](size_t bytes) { char* p = ws + off; off += (bytes + 255) & ~(size_t)255; return p; };
  int*   padOff    = (int*)alloc(64);
  int*   blockHist = (int*)alloc((size_t)NBLK * NEXP * 4);
  int*   base      = (int*)alloc((size_t)NBLK * NEXP * 4);
  int*   sel       = (int*)alloc((size_t)2 * T_TOK * 4);
  float* selw      = (float*)alloc((size_t)2 * T_TOK * 4);
  int*   rowTok    = (int*)alloc((size_t)MAXROWS * 4);
  int*   rowSlot   = (int*)alloc((size_t)MAXROWS * 4);
  unsigned short* xbf   = (unsigned short*)alloc((size_t)T_TOK * DIM * 2);           // 64 MiB
  unsigned short* w13bf = (unsigned short*)alloc((size_t)NEXP * 2 * DFFN * DIM * 2); // 64 MiB
  unsigned short* w2bf  = (unsigned short*)alloc((size_t)NEXP * DIM * DFFN * 2);     // 32 MiB
  unsigned short* Hbuf  = (unsigned short*)alloc((size_t)MAXROWS * DFFN * 2);        // 264 MiB
  unsigned short* Oslot = xbf;  // 128 MiB alias over xbf+w13bf (dead after gemm1)

  route_kernel<<<NBLK, 256, 0, stream>>>(gating, sel, selw, blockHist);
  plan_kernel<<<1, 64, 0, stream>>>(blockHist, padOff, base);
  fill_kernel<<<MAXROWS / 256, 256, 0, stream>>>(rowTok, rowSlot);
  scatter_kernel<<<NBLK, 256, 0, stream>>>(sel, base, rowTok, rowSlot);
  cvt3_kernel<<<2048, 256, 0, stream>>>(x, xbf, T_TOK * DIM / 4,
                                        w13, w13bf, NEXP * 2 * DFFN * DIM / 4,
                                        w2, w2bf, NEXP * DIM * DFFN / 4);
  gemm1_kernel<<<dim3(2 * DFFN / 256, MAXROWS / 256), 512, 0, stream>>>(xbf, w13bf, rowTok, padOff, Hbuf);
  gemm2_kernel<<<dim3(DIM / 256, MAXROWS / 256), 512, 0, stream>>>(Hbuf, w2bf, rowSlot, padOff, Oslot);
  combine_kernel<<<T_TOK * DIM / 8 / 256, 256, 0, stream>>>(Oslot, selw, out);
}